// Round 1
// baseline (7687.766 us; speedup 1.0000x reference)
//
#include <hip/hip_runtime.h>

// ---------------- problem constants ----------------
#define T_DIM 512
#define B_DIM 256
#define D_DIM 512
#define H_DIM 512
#define TB_DIM (T_DIM * B_DIM)   // 131072 (GEMM M)
#define NG_DIM (4 * H_DIM)       // 2048   (GEMM N, 4 gates concat)

typedef _Float16 half_t;
typedef _Float16 v8h __attribute__((ext_vector_type(8)));
typedef _Float16 v4h __attribute__((ext_vector_type(4)));
typedef float v4f __attribute__((ext_vector_type(4)));

// async global->LDS, 16B per lane (global_load_lds_dwordx4)
__device__ __forceinline__ void async_ld16(void* lds, const void* gsrc) {
  __builtin_amdgcn_global_load_lds((__attribute__((address_space(1))) void*)gsrc,
                                   (__attribute__((address_space(3))) void*)lds,
                                   16, 0, 0);
}

__device__ __forceinline__ float sigmoid_f(float x) {
  return 1.0f / (1.0f + __expf(-x));
}
__device__ __forceinline__ float tanh_f(float x) {
  // 1 - 2/(e^{2x}+1); overflow-safe (exp->inf => 1, exp->0 => -1)
  float e = __expf(2.0f * x);
  return 1.0f - 2.0f / (e + 1.0f);
}

// ---------------- converts ----------------
__global__ __launch_bounds__(256) void k_convX(const float4* __restrict__ X,
                                               v4h* __restrict__ Xh, int n4) {
  int i = blockIdx.x * 256 + threadIdx.x;
  if (i < n4) {
    float4 v = X[i];
    v4h o;
    o[0] = (half_t)v.x; o[1] = (half_t)v.y; o[2] = (half_t)v.z; o[3] = (half_t)v.w;
    Xh[i] = o;
  }
}

// builds Wcat16 [2048][512] (f,i,o,a concatenated) and Waa16 [512][512]
__global__ __launch_bounds__(256) void k_convW(const float4* __restrict__ wf,
                                               const float4* __restrict__ wi,
                                               const float4* __restrict__ wo,
                                               const float4* __restrict__ wa,
                                               const float4* __restrict__ waa,
                                               v4h* __restrict__ Wcat,
                                               v4h* __restrict__ Waa16) {
  int idx = blockIdx.x * 256 + threadIdx.x;   // over 5*65536 float4s
  int chunk = idx >> 16;
  int off = idx & 65535;
  const float4* src = (chunk == 0) ? wf : (chunk == 1) ? wi : (chunk == 2) ? wo
                      : (chunk == 3) ? wa : waa;
  float4 v = src[off];
  v4h o;
  o[0] = (half_t)v.x; o[1] = (half_t)v.y; o[2] = (half_t)v.z; o[3] = (half_t)v.w;
  if (chunk < 4) Wcat[chunk * 65536 + off] = o;
  else           Waa16[off] = o;
}

// bsum[col], col = g*512+j: g in {f,i,o}: b_g + b_a ; g==3 (a-gate): b_a
__global__ __launch_bounds__(256) void k_bias(const float* __restrict__ bf,
                                              const float* __restrict__ bi,
                                              const float* __restrict__ bo,
                                              const float* __restrict__ ba,
                                              float* __restrict__ bsum) {
  int i = blockIdx.x * 256 + threadIdx.x;  // 2048
  int g = i >> 9, j = i & 511;
  float v = ba[j];
  if (g == 0) v += bf[j];
  else if (g == 1) v += bi[j];
  else if (g == 2) v += bo[j];
  bsum[i] = v;
}

// ---------------- phase 1: gates = X @ Wcat^T + bsum (fp16 MFMA) ----------------
// 128x128 tile, BK=32, 4 waves each 64x64, m97-style staging.
__global__ __launch_bounds__(256) void k_gemm_gates(
    const half_t* __restrict__ A,    // Xh [TB][512]
    const half_t* __restrict__ Bm,   // Wcat [2048][512]
    const float* __restrict__ bsum,  // [2048]
    half_t* __restrict__ gates) {    // [4][TB][512]
  __shared__ __align__(16) half_t lA[128 * 32];
  __shared__ __align__(16) half_t lB[128 * 32];
  const int tid = threadIdx.x;
  const int l = tid & 63;
  const int w = tid >> 6;
  const int m0 = blockIdx.x * 128;
  const int n0 = blockIdx.y * 128;
  const int wm = (w >> 1) * 64;
  const int wn = (w & 1) * 64;
  const int lr = l & 15;
  const int lk = (l >> 4) * 8;

  v4f acc[4][4];
#pragma unroll
  for (int i = 0; i < 4; i++)
#pragma unroll
    for (int j = 0; j < 4; j++) acc[i][j] = (v4f){0.f, 0.f, 0.f, 0.f};

  const int row_in = tid >> 2;        // 0..63
  const int kc_in = (tid & 3) * 8;    // fp16 elems within BK

  for (int kt = 0; kt < 16; ++kt) {
    const int k0 = kt * 32;
    __syncthreads();
    async_ld16(&lA[tid * 8],        &A[(size_t)(m0 + row_in) * 512 + k0 + kc_in]);
    async_ld16(&lA[2048 + tid * 8], &A[(size_t)(m0 + 64 + row_in) * 512 + k0 + kc_in]);
    async_ld16(&lB[tid * 8],        &Bm[(size_t)(n0 + row_in) * 512 + k0 + kc_in]);
    async_ld16(&lB[2048 + tid * 8], &Bm[(size_t)(n0 + 64 + row_in) * 512 + k0 + kc_in]);
    __syncthreads();

    v8h af[4], bfr[4];
#pragma unroll
    for (int tm = 0; tm < 4; tm++)
      af[tm] = *(const v8h*)&lA[(wm + tm * 16 + lr) * 32 + lk];
#pragma unroll
    for (int tn = 0; tn < 4; tn++)
      bfr[tn] = *(const v8h*)&lB[(wn + tn * 16 + lr) * 32 + lk];
#pragma unroll
    for (int tm = 0; tm < 4; tm++)
#pragma unroll
      for (int tn = 0; tn < 4; tn++)
        acc[tm][tn] = __builtin_amdgcn_mfma_f32_16x16x32_f16(af[tm], bfr[tn],
                                                             acc[tm][tn], 0, 0, 0);
  }

  // epilogue: C/D layout col=lane&15, row=(lane>>4)*4+r  (m89/m91-verified)
#pragma unroll
  for (int tn = 0; tn < 4; tn++) {
    const int col = n0 + wn + tn * 16 + lr;   // virtual col in [0,2048)
    const int g = col >> 9;
    const int j = col & 511;
    const float bias = bsum[col];
    half_t* outg = gates + (size_t)g * TB_DIM * 512 + j;
#pragma unroll
    for (int tm = 0; tm < 4; tm++) {
      const int r0 = m0 + wm + tm * 16 + (l >> 4) * 4;
#pragma unroll
      for (int r = 0; r < 4; r++)
        outg[(size_t)(r0 + r) * 512] = (half_t)(acc[tm][tn][r] + bias);
    }
  }
}

// ---------------- phase 2: one step ----------------
// a = h_prev @ Waa^T (fp16 MFMA, LDS-free), then fused gate elementwise.
// 128 blocks x 64 threads: block = (b-tile 32) x (j-tile 32).
__global__ __launch_bounds__(64) void k_step(
    const half_t* __restrict__ hin,    // [256][512] fp16
    const half_t* __restrict__ Waa,    // [512][512] fp16
    const half_t* __restrict__ gates,  // [4][TB][512] fp16 (biases folded)
    float* __restrict__ c,             // [256][512]
    float* __restrict__ out,           // d_out [T][256][512]
    half_t* __restrict__ hout,         // [256][512] fp16
    int t) {
  const int l = threadIdx.x;
  const int b0 = (blockIdx.x >> 4) * 32;
  const int j0 = (blockIdx.x & 15) * 32;
  const int lr = l & 15;
  const int lk = (l >> 4) * 8;

  v4f acc[2][2];
#pragma unroll
  for (int i = 0; i < 2; i++)
#pragma unroll
    for (int j = 0; j < 2; j++) acc[i][j] = (v4f){0.f, 0.f, 0.f, 0.f};

#pragma unroll
  for (int kc = 0; kc < 16; ++kc) {
    const int k = kc * 32 + lk;
    v8h a0 = *(const v8h*)&hin[(b0 + lr) * 512 + k];
    v8h a1 = *(const v8h*)&hin[(b0 + 16 + lr) * 512 + k];
    v8h w0 = *(const v8h*)&Waa[(j0 + lr) * 512 + k];
    v8h w1 = *(const v8h*)&Waa[(j0 + 16 + lr) * 512 + k];
    acc[0][0] = __builtin_amdgcn_mfma_f32_16x16x32_f16(a0, w0, acc[0][0], 0, 0, 0);
    acc[0][1] = __builtin_amdgcn_mfma_f32_16x16x32_f16(a0, w1, acc[0][1], 0, 0, 0);
    acc[1][0] = __builtin_amdgcn_mfma_f32_16x16x32_f16(a1, w0, acc[1][0], 0, 0, 0);
    acc[1][1] = __builtin_amdgcn_mfma_f32_16x16x32_f16(a1, w1, acc[1][1], 0, 0, 0);
  }

  const size_t gstride = (size_t)TB_DIM * 512;
  const size_t gtbase = (size_t)t * B_DIM * 512;
#pragma unroll
  for (int tm = 0; tm < 2; tm++) {
#pragma unroll
    for (int tn = 0; tn < 2; tn++) {
      const int j = j0 + tn * 16 + lr;
#pragma unroll
      for (int r = 0; r < 4; r++) {
        const int b = b0 + tm * 16 + (l >> 4) * 4 + r;
        const float a = acc[tm][tn][r];
        const size_t gi = gtbase + (size_t)b * 512 + j;
        const float xf = (float)gates[gi];
        const float xi = (float)gates[gstride + gi];
        const float xo = (float)gates[2 * gstride + gi];
        const float xa = (float)gates[3 * gstride + gi];
        const float ft = sigmoid_f(xf + a);
        const float it = sigmoid_f(xi + a);
        const float ot = sigmoid_f(xo + a);
        const float gg = tanh_f(xa + a);
        const int ci = b * 512 + j;
        const float cn = ft * c[ci] + it * gg;
        c[ci] = cn;
        const float hn = ot * tanh_f(cn);
        out[(size_t)t * (B_DIM * H_DIM) + ci] = hn;
        hout[ci] = (half_t)hn;
      }
    }
  }
}

// ---------------- host ----------------
extern "C" void kernel_launch(void* const* d_in, const int* in_sizes, int n_in,
                              void* d_out, int out_size, void* d_ws, size_t ws_size,
                              hipStream_t stream) {
  const float* X = (const float*)d_in[0];
  const float* Wf = (const float*)d_in[1];
  const float* Wi = (const float*)d_in[2];
  const float* Wo = (const float*)d_in[3];
  const float* Wa = (const float*)d_in[4];
  const float* Waa = (const float*)d_in[5];
  const float* bf = (const float*)d_in[6];
  const float* bi = (const float*)d_in[7];
  const float* bo = (const float*)d_in[8];
  const float* ba = (const float*)d_in[9];
  float* out = (float*)d_out;

  char* ws = (char*)d_ws;
  // workspace layout (bytes)
  half_t* Xh    = (half_t*)(ws + 0);           // 134217728  [TB][512] fp16
  half_t* gates = (half_t*)(ws + 134217728);   // 536870912  [4][TB][512] fp16
  half_t* Wcat  = (half_t*)(ws + 671088640);   // 2097152    [2048][512] fp16
  half_t* Waa16 = (half_t*)(ws + 673185792);   // 524288     [512][512] fp16
  float*  bsum  = (float*)(ws + 673710080);    // 8192       [2048]
  float*  cbuf  = (float*)(ws + 673718272);    // 524288     [256][512] fp32
  half_t* hbuf  = (half_t*)(ws + 674242560);   // 524288     2x[256][512] fp16
  // total: ~643.5 MB

  // zero-init state (ws is poisoned 0xAA before every timed launch)
  hipMemsetAsync(cbuf, 0, (size_t)B_DIM * H_DIM * 4, stream);
  hipMemsetAsync(hbuf, 0, (size_t)B_DIM * H_DIM * 2, stream);

  k_convX<<<65536, 256, 0, stream>>>((const float4*)X, (v4h*)Xh, 16777216);
  k_convW<<<1280, 256, 0, stream>>>((const float4*)Wf, (const float4*)Wi,
                                    (const float4*)Wo, (const float4*)Wa,
                                    (const float4*)Waa, (v4h*)Wcat, (v4h*)Waa16);
  k_bias<<<8, 256, 0, stream>>>(bf, bi, bo, ba, bsum);

  k_gemm_gates<<<dim3(TB_DIM / 128, NG_DIM / 128), 256, 0, stream>>>(Xh, Wcat, bsum,
                                                                     gates);

  for (int t = 0; t < T_DIM; ++t) {
    const half_t* hin = hbuf + (size_t)(t & 1) * (B_DIM * H_DIM);
    half_t* hout = hbuf + (size_t)((t + 1) & 1) * (B_DIM * H_DIM);
    k_step<<<128, 64, 0, stream>>>(hin, Waa16, gates, cbuf, out, hout, t);
  }

  // h_n = outputs[T-1]
  hipMemcpyAsync(out + (size_t)TB_DIM * H_DIM / 1 * 0 + (size_t)T_DIM * B_DIM * H_DIM,
                 out + (size_t)(T_DIM - 1) * B_DIM * H_DIM,
                 (size_t)B_DIM * H_DIM * sizeof(float), hipMemcpyDeviceToDevice,
                 stream);
}